// Round 1
// baseline (21723.657 us; speedup 1.0000x reference)
//
#include <hip/hip_runtime.h>
#include <hip/hip_bf16.h>
#include <cstddef>

#define BQ 4
#define LQ 2048
#define DQ 512
#define HQ 8
#define HDQ 64
#define KQ 5
#define MAXMQ 10

// ---------------- embedding: x = tok_emb[ids] + pos_emb ----------------
__global__ __launch_bounds__(256) void embed_kernel(const int* __restrict__ tok,
    const float* __restrict__ te, const float* __restrict__ pe, float* __restrict__ x) {
  int row = blockIdx.x;              // b*L + l
  int l = row & (LQ - 1);
  int t = tok[row];
  const float* trow = te + (size_t)t * DQ;
  const float* prow = pe + (size_t)l * DQ;
  float* xr = x + (size_t)row * DQ;
  for (int d = threadIdx.x; d < DQ; d += 256)
    xr[d] = trow[d] + prow[d];
}

// ---------------- generic tiled GEMM: C = act(A @ W^T + bias + R) ----------------
// A: [M,K] f32.  W: WT ? [N,K] : [K,N].  bias: [N] or nullptr.  R: [M,N] residual.
template<bool WT, bool RELU, bool HASRES>
__global__ __launch_bounds__(256) void gemm_kernel(
    const float* __restrict__ A, const float* __restrict__ W,
    const float* __restrict__ bias, const float* __restrict__ R,
    float* __restrict__ C, int M, int N, int Kd) {
  __shared__ float As[64][36];
  __shared__ float Ws[64][36];
  int tid = threadIdx.x;
  int tx = tid & 15, ty = tid >> 4;
  int m0 = blockIdx.y * 64, n0 = blockIdx.x * 64;
  float acc[4][4] = {};
  for (int k0 = 0; k0 < Kd; k0 += 32) {
    #pragma unroll
    for (int i = 0; i < 8; ++i) {
      int idx = tid + i * 256;
      int r = idx >> 5, c = idx & 31;
      int gm = m0 + r;
      As[r][c] = (gm < M) ? A[(size_t)gm * Kd + k0 + c] : 0.f;
    }
    #pragma unroll
    for (int i = 0; i < 8; ++i) {
      int idx = tid + i * 256;
      int r = idx >> 5, c = idx & 31;
      int gn = n0 + r;
      float wv = 0.f;
      if (gn < N) wv = WT ? W[(size_t)gn * Kd + k0 + c] : W[(size_t)(k0 + c) * N + gn];
      Ws[r][c] = wv;
    }
    __syncthreads();
    #pragma unroll
    for (int kk = 0; kk < 32; kk += 4) {
      float4 a[4], w[4];
      #pragma unroll
      for (int i = 0; i < 4; ++i) a[i] = *(const float4*)&As[ty * 4 + i][kk];
      #pragma unroll
      for (int j = 0; j < 4; ++j) w[j] = *(const float4*)&Ws[tx * 4 + j][kk];
      #pragma unroll
      for (int i = 0; i < 4; ++i)
        #pragma unroll
        for (int j = 0; j < 4; ++j)
          acc[i][j] += a[i].x * w[j].x + a[i].y * w[j].y + a[i].z * w[j].z + a[i].w * w[j].w;
    }
    __syncthreads();
  }
  #pragma unroll
  for (int i = 0; i < 4; ++i) {
    int gm = m0 + ty * 4 + i;
    if (gm >= M) continue;
    #pragma unroll
    for (int j = 0; j < 4; ++j) {
      int gn = n0 + tx * 4 + j;
      float v = acc[i][j];
      if (bias) v += bias[gn];
      if (HASRES) v += R[(size_t)gm * N + gn];
      if (RELU) v = fmaxf(v, 0.f);
      C[(size_t)gm * N + gn] = v;
    }
  }
}

// ---------------- attention: one wave per query row, online softmax ----------------
// qkv: [B,L,3D], q at col h*64+d, k at 512+h*64+d, v at 1024+h*64+d. o: [B,L,D]
__global__ __launch_bounds__(256) void attn_kernel(const float* __restrict__ qkv,
                                                   float* __restrict__ o) {
  int lane = threadIdx.x & 63;
  int l = blockIdx.x * 4 + (threadIdx.x >> 6);
  int bh = blockIdx.y;
  int b = bh >> 3, h = bh & 7;
  const float* base = qkv + (size_t)b * LQ * (3 * DQ);
  float q = base[(size_t)l * (3 * DQ) + h * HDQ + lane] * 0.125f;  // 1/sqrt(64)
  float m = -1e30f, se = 0.f, acc = 0.f;
  for (int j = 0; j < LQ; ++j) {
    const float* kj = base + (size_t)j * (3 * DQ) + DQ + h * HDQ;
    float kv = kj[lane];
    float vv = kj[DQ + lane];
    float p = q * kv;
    #pragma unroll
    for (int off = 32; off; off >>= 1) p += __shfl_xor(p, off);
    float nm = fmaxf(m, p);
    float cor = __expf(m - nm);
    float pe = __expf(p - nm);
    se = se * cor + pe;
    acc = acc * cor + pe * vv;
    m = nm;
  }
  o[((size_t)(b * LQ + l)) * DQ + h * HDQ + lane] = acc / se;
}

// ---------------- LayerNorm over D=512, one block per row ----------------
__global__ __launch_bounds__(256) void ln_kernel(const float* __restrict__ t,
    const float* __restrict__ g, const float* __restrict__ bb, float* __restrict__ xo) {
  int row = blockIdx.x;
  const float* tr = t + (size_t)row * DQ;
  int tid = threadIdx.x;
  float v0 = tr[tid], v1 = tr[tid + 256];
  float s = v0 + v1, ss = v0 * v0 + v1 * v1;
  #pragma unroll
  for (int off = 32; off; off >>= 1) { s += __shfl_xor(s, off); ss += __shfl_xor(ss, off); }
  __shared__ float rs[4], rss[4];
  int w = tid >> 6;
  if ((tid & 63) == 0) { rs[w] = s; rss[w] = ss; }
  __syncthreads();
  s = rs[0] + rs[1] + rs[2] + rs[3];
  ss = rss[0] + rss[1] + rss[2] + rss[3];
  float mean = s * (1.f / 512.f);
  float var = ss * (1.f / 512.f) - mean * mean;
  float r = rsqrtf(var + 1e-5f);
  float* xr = xo + (size_t)row * DQ;
  xr[tid]       = (v0 - mean) * r * g[tid]       + bb[tid];
  xr[tid + 256] = (v1 - mean) * r * g[tid + 256] + bb[tid + 256];
}

// ---------------- start/end logits: one wave per row ----------------
__global__ __launch_bounds__(256) void logits_kernel(const float* __restrict__ hidden,
    const float* __restrict__ sw, const float* __restrict__ sb,
    const float* __restrict__ ew, const float* __restrict__ eb,
    float* __restrict__ osl, float* __restrict__ oel) {
  int row = blockIdx.x * 4 + (threadIdx.x >> 6);
  int lane = threadIdx.x & 63;
  const float* hr = hidden + (size_t)row * DQ;
  float a = 0.f, b2 = 0.f;
  #pragma unroll
  for (int i = 0; i < 8; ++i) {
    int d = lane + i * 64;
    float h = hr[d];
    a += h * sw[d];
    b2 += h * ew[d];
  }
  #pragma unroll
  for (int off = 32; off; off >>= 1) { a += __shfl_xor(a, off); b2 += __shfl_xor(b2, off); }
  if (lane == 0) { osl[row] = a + sb[0]; oel[row] = b2 + eb[0]; }
}

// ---------------- top-5 per (b, which): wave-parallel repeated argmax ----------------
// tie-break: equal value -> smaller index (matches jax.lax.top_k stability)
__global__ void topk_kernel(const float* __restrict__ slog, const float* __restrict__ elog,
                            int* __restrict__ sidx, int* __restrict__ eidx) {
  int b = blockIdx.x & 3;
  int which = blockIdx.x >> 2;
  const float* lg = (which ? elog : slog) + (size_t)b * LQ;
  int* outp = (which ? eidx : sidx) + b * KQ;
  int lane = threadIdx.x;
  int ch[KQ];
  for (int k = 0; k < KQ; ++k) {
    float bv = -1e38f; int bi = 1 << 30;
    for (int i = lane; i < LQ; i += 64) {
      bool skip = false;
      for (int t = 0; t < k; ++t) if (ch[t] == i) skip = true;
      float v = lg[i];
      if (!skip && (v > bv || (v == bv && i < bi))) { bv = v; bi = i; }
    }
    #pragma unroll
    for (int off = 32; off; off >>= 1) {
      float ov = __shfl_xor(bv, off); int oi = __shfl_xor(bi, off);
      if (ov > bv || (ov == bv && oi < bi)) { bv = ov; bi = oi; }
    }
    ch[k] = bi;
    if (lane == 0) outp[k] = bi;
  }
}

// ---------------- validity + stable compaction order ----------------
__global__ void vo_kernel(const int* __restrict__ sidx, const int* __restrict__ eidx,
                          int* __restrict__ order, int* __restrict__ vs) {
  int b = threadIdx.x;
  if (b >= BQ) return;
  int val[KQ];
  for (int k = 0; k < KQ; ++k) {
    int s = sidx[b * KQ + k], e = eidx[b * KQ + k];
    val[k] = (e >= s && (e - s) < MAXMQ) ? 1 : 0;
  }
  int j = 0;
  for (int k = 0; k < KQ; ++k) if (val[k])  { order[b * KQ + j] = k; vs[b * KQ + j] = 1; ++j; }
  for (int k = 0; k < KQ; ++k) if (!val[k]) { order[b * KQ + j] = k; vs[b * KQ + j] = 0; ++j; }
}

// ---------------- span features: [h_s, h_e, h_s*h_e] ----------------
__global__ __launch_bounds__(256) void feat_kernel(const float* __restrict__ hidden,
    const int* __restrict__ sidx, const int* __restrict__ eidx, float* __restrict__ feat) {
  int row = blockIdx.x;            // b*K + k
  int b = row / KQ;
  int si = sidx[row], ei = eidx[row];
  const float* hs = hidden + ((size_t)(b * LQ + si)) * DQ;
  const float* he = hidden + ((size_t)(b * LQ + ei)) * DQ;
  float* fr = feat + (size_t)row * (3 * DQ);
  for (int d = threadIdx.x; d < DQ; d += 256) {
    float a = hs[d], c = he[d];
    fr[d] = a; fr[DQ + d] = c; fr[2 * DQ + d] = a * c;
  }
}

// ---------------- compact valid spans to front, zero the rest ----------------
__global__ __launch_bounds__(256) void compact_kernel(const float* __restrict__ spanraw,
    const int* __restrict__ order, const int* __restrict__ vs, float* __restrict__ outspan) {
  int row = blockIdx.x;            // b*K + j
  int b = row / KQ;
  int src = b * KQ + order[row];
  float keep = vs[row] ? 1.f : 0.f;
  for (int d = threadIdx.x; d < DQ; d += 256)
    outspan[(size_t)row * DQ + d] = spanraw[(size_t)src * DQ + d] * keep;
}

// ---------------- scores: (mp @ entity_w) . cand + mp . entity_b ----------------
__global__ __launch_bounds__(256) void scores_kernel(const float* __restrict__ cand,
    const float* __restrict__ mp, const float* __restrict__ u, const float* __restrict__ ebias,
    float* __restrict__ oscores) {
  int gw = blockIdx.x * 4 + (threadIdx.x >> 6);   // 0..1279 = (b*K+j)*64 + c
  int lane = threadIdx.x & 63;
  int bj = gw >> 6;
  const float* ce = cand + (size_t)gw * DQ;
  const float* ur = u + (size_t)bj * DQ;
  const float* mr = mp + (size_t)bj * DQ;
  float s = 0.f;
  #pragma unroll
  for (int i = 0; i < 8; ++i) {
    int e = lane + i * 64;
    s += ce[e] * ur[e] + mr[e] * ebias[e];
  }
  #pragma unroll
  for (int off = 32; off; off >>= 1) s += __shfl_xor(s, off);
  if (lane == 0) oscores[gw] = s;
}

extern "C" void kernel_launch(void* const* d_in, const int* in_sizes, int n_in,
                              void* d_out, int out_size, void* d_ws, size_t ws_size,
                              hipStream_t stream) {
  const int*   token_ids = (const int*)d_in[0];
  const float* cand    = (const float*)d_in[1];
  const float* tok_emb = (const float*)d_in[2];
  const float* pos_emb = (const float*)d_in[3];
  const float* ain_w   = (const float*)d_in[4];   // [2,1536,512]
  const float* ain_b   = (const float*)d_in[5];   // [2,1536]
  const float* aout_w  = (const float*)d_in[6];   // [2,512,512]
  const float* aout_b  = (const float*)d_in[7];
  const float* ln1g    = (const float*)d_in[8];
  const float* ln1b    = (const float*)d_in[9];
  const float* fw1     = (const float*)d_in[10];  // [2,2048,512]
  const float* fb1     = (const float*)d_in[11];
  const float* fw2     = (const float*)d_in[12];  // [2,512,2048]
  const float* fb2     = (const float*)d_in[13];
  const float* ln2g    = (const float*)d_in[14];
  const float* ln2b    = (const float*)d_in[15];
  const float* sw      = (const float*)d_in[16];
  const float* sb      = (const float*)d_in[17];
  const float* ew      = (const float*)d_in[18];
  const float* eb      = (const float*)d_in[19];
  const float* sp_w1   = (const float*)d_in[20];  // [512,1536]
  const float* sp_b1   = (const float*)d_in[21];
  const float* sp_w2   = (const float*)d_in[22];  // [512,512]
  const float* sp_b2   = (const float*)d_in[23];
  const float* m_w     = (const float*)d_in[24];
  const float* m_b     = (const float*)d_in[25];
  const float* e_w     = (const float*)d_in[26];
  const float* e_b     = (const float*)d_in[27];

  const int M = BQ * LQ;           // 8192
  float* out = (float*)d_out;
  float* out_span   = out;                  // [4,5,512]   = 10240
  float* out_sl     = out + 10240;          // [4,2048]    = 8192
  float* out_el     = out + 18432;          // [4,2048]    = 8192
  float* out_hidden = out + 26624;          // [4,2048,512]= 4194304
  float* out_scores = out + 4220928;        // [4,5,64]    = 1280

  float* ws  = (float*)d_ws;
  float* X   = ws;                          // [8192,512]
  float* T   = ws + 4194304;                // [8192,512]
  float* O   = ws + 8388608;                // [8192,512]
  float* BIG = ws + 12582912;               // [8192,2048] (qkv uses [8192,1536])
  int*   SIDX  = (int*)(ws + 29360128);     // 20
  int*   EIDX  = SIDX + 20;
  int*   ORDER = EIDX + 20;
  int*   VS    = ORDER + 20;
  float* FEAT    = ws + 29360208;           // [20,1536]
  float* SPANH   = FEAT + 20 * 1536;        // [20,512]
  float* SPANRAW = SPANH + 10240;           // [20,512]
  float* MP      = SPANRAW + 10240;         // [20,512]
  float* U       = MP + 10240;              // [20,512]

  embed_kernel<<<M, 256, 0, stream>>>(token_ids, tok_emb, pos_emb, X);

  for (int l = 0; l < 2; ++l) {
    // qkv = x @ in_w^T + in_b
    gemm_kernel<true, false, false><<<dim3(24, 128), 256, 0, stream>>>(
        X, ain_w + (size_t)l * 1536 * 512, ain_b + l * 1536, nullptr, BIG, M, 1536, 512);
    // attention
    attn_kernel<<<dim3(LQ / 4, BQ * HQ), 256, 0, stream>>>(BIG, O);
    // t = x + o @ out_w^T + out_b
    gemm_kernel<true, false, true><<<dim3(8, 128), 256, 0, stream>>>(
        O, aout_w + (size_t)l * 512 * 512, aout_b + l * 512, X, T, M, 512, 512);
    ln_kernel<<<M, 256, 0, stream>>>(T, ln1g + l * 512, ln1b + l * 512, X);
    // ffn
    gemm_kernel<true, true, false><<<dim3(32, 128), 256, 0, stream>>>(
        X, fw1 + (size_t)l * 2048 * 512, fb1 + l * 2048, nullptr, BIG, M, 2048, 512);
    gemm_kernel<true, false, true><<<dim3(8, 128), 256, 0, stream>>>(
        BIG, fw2 + (size_t)l * 512 * 2048, fb2 + l * 512, X, T, M, 512, 2048);
    ln_kernel<<<M, 256, 0, stream>>>(T, ln2g + l * 512, ln2b + l * 512, X);
  }

  // heads
  logits_kernel<<<M / 4, 256, 0, stream>>>(X, sw, sb, ew, eb, out_sl, out_el);
  topk_kernel<<<8, 64, 0, stream>>>(out_sl, out_el, SIDX, EIDX);
  vo_kernel<<<1, 64, 0, stream>>>(SIDX, EIDX, ORDER, VS);
  feat_kernel<<<20, 256, 0, stream>>>(X, SIDX, EIDX, FEAT);
  gemm_kernel<true, true, false><<<dim3(8, 1), 256, 0, stream>>>(
      FEAT, sp_w1, sp_b1, nullptr, SPANH, 20, 512, 1536);
  gemm_kernel<true, false, false><<<dim3(8, 1), 256, 0, stream>>>(
      SPANH, sp_w2, sp_b2, nullptr, SPANRAW, 20, 512, 512);
  compact_kernel<<<20, 256, 0, stream>>>(SPANRAW, ORDER, VS, out_span);
  gemm_kernel<true, false, false><<<dim3(8, 1), 256, 0, stream>>>(
      out_span, m_w, m_b, nullptr, MP, 20, 512, 512);
  // u = mp @ entity_w  (W not transposed)
  gemm_kernel<false, false, false><<<dim3(8, 1), 256, 0, stream>>>(
      MP, e_w, nullptr, nullptr, U, 20, 512, 512);
  scores_kernel<<<320, 256, 0, stream>>>(cand, MP, U, e_b, out_scores);

  // hidden output (f32 copy)
  hipMemcpyAsync(out_hidden, X, (size_t)M * DQ * sizeof(float),
                 hipMemcpyDeviceToDevice, stream);
}

// Round 2
// 5657.194 us; speedup vs baseline: 3.8400x; 3.8400x over previous
//
#include <hip/hip_runtime.h>
#include <hip/hip_bf16.h>
#include <cstddef>

#define BQ 4
#define LQ 2048
#define DQ 512
#define HQ 8
#define HDQ 64
#define KQ 5
#define MAXMQ 10

typedef __attribute__((ext_vector_type(8))) __bf16 bf16x8;
typedef __attribute__((ext_vector_type(4))) float f32x4;

// ---------------- embedding: x = tok_emb[ids] + pos_emb ----------------
__global__ __launch_bounds__(256) void embed_kernel(const int* __restrict__ tok,
    const float* __restrict__ te, const float* __restrict__ pe, float* __restrict__ x) {
  int row = blockIdx.x;              // b*L + l
  int l = row & (LQ - 1);
  int t = tok[row];
  const float* trow = te + (size_t)t * DQ;
  const float* prow = pe + (size_t)l * DQ;
  float* xr = x + (size_t)row * DQ;
  for (int d = threadIdx.x; d < DQ; d += 256)
    xr[d] = trow[d] + prow[d];
}

// ---------------- generic tiled GEMM: C = act(A @ W^T + bias + R) ----------------
template<bool WT, bool RELU, bool HASRES>
__global__ __launch_bounds__(256) void gemm_kernel(
    const float* __restrict__ A, const float* __restrict__ W,
    const float* __restrict__ bias, const float* __restrict__ R,
    float* __restrict__ C, int M, int N, int Kd) {
  __shared__ float As[64][36];
  __shared__ float Ws[64][36];
  int tid = threadIdx.x;
  int tx = tid & 15, ty = tid >> 4;
  int m0 = blockIdx.y * 64, n0 = blockIdx.x * 64;
  float acc[4][4] = {};
  for (int k0 = 0; k0 < Kd; k0 += 32) {
    #pragma unroll
    for (int i = 0; i < 8; ++i) {
      int idx = tid + i * 256;
      int r = idx >> 5, c = idx & 31;
      int gm = m0 + r;
      As[r][c] = (gm < M) ? A[(size_t)gm * Kd + k0 + c] : 0.f;
    }
    #pragma unroll
    for (int i = 0; i < 8; ++i) {
      int idx = tid + i * 256;
      int r = idx >> 5, c = idx & 31;
      int gn = n0 + r;
      float wv = 0.f;
      if (gn < N) wv = WT ? W[(size_t)gn * Kd + k0 + c] : W[(size_t)(k0 + c) * N + gn];
      Ws[r][c] = wv;
    }
    __syncthreads();
    #pragma unroll
    for (int kk = 0; kk < 32; kk += 4) {
      float4 a[4], w[4];
      #pragma unroll
      for (int i = 0; i < 4; ++i) a[i] = *(const float4*)&As[ty * 4 + i][kk];
      #pragma unroll
      for (int j = 0; j < 4; ++j) w[j] = *(const float4*)&Ws[tx * 4 + j][kk];
      #pragma unroll
      for (int i = 0; i < 4; ++i)
        #pragma unroll
        for (int j = 0; j < 4; ++j)
          acc[i][j] += a[i].x * w[j].x + a[i].y * w[j].y + a[i].z * w[j].z + a[i].w * w[j].w;
    }
    __syncthreads();
  }
  #pragma unroll
  for (int i = 0; i < 4; ++i) {
    int gm = m0 + ty * 4 + i;
    if (gm >= M) continue;
    #pragma unroll
    for (int j = 0; j < 4; ++j) {
      int gn = n0 + tx * 4 + j;
      float v = acc[i][j];
      if (bias) v += bias[gn];
      if (HASRES) v += R[(size_t)gm * N + gn];
      if (RELU) v = fmaxf(v, 0.f);
      C[(size_t)gm * N + gn] = v;
    }
  }
}

// ---------------- MFMA flash attention ----------------
// Block: 256 threads = 4 waves; one (b,h), 64 query rows (16 per wave).
// qkv: [B,L,3D] f32 (q at h*64, k at 512+h*64, v at 1024+h*64). o: [B,L,D] f32.
// mfma_f32_16x16x32_bf16 layouts: A row=lane&15, k=(lane>>4)*8+j;
// B col=lane&15, k=(lane>>4)*8+j; C/D row=(lane>>4)*4+reg, col=lane&15 (m89).
__global__ __launch_bounds__(256) void attn_mfma_kernel(const float* __restrict__ qkv,
                                                        float* __restrict__ o) {
  __shared__ __bf16 Ks[64][72];       // [key][d], pad to 144B rows (9x16B)
  __shared__ __bf16 Vt[64][72];       // [d][key], col-block XOR swizzled
  __shared__ __bf16 Ps[4][16][72];    // per-wave P tile [q][key]

  const int tid = threadIdx.x;
  const int wave = tid >> 6;
  const int lane = tid & 63;
  const int lr = lane & 15;
  const int lg = lane >> 4;
  const int bh = blockIdx.y;
  const int b = bh >> 3, h = bh & 7;
  const int q0 = blockIdx.x * 64;

  const float* base = qkv + (size_t)b * LQ * 1536;

  // Q fragment (scaled by 1/sqrt(64)): rows q0+wave*16+lr, d = 32c + lg*8 + j
  bf16x8 aq[2];
  {
    const int qrow = q0 + wave * 16 + lr;
    const float* qp = base + (size_t)qrow * 1536 + h * 64 + lg * 8;
    #pragma unroll
    for (int c = 0; c < 2; ++c) {
      float4 f0 = *(const float4*)(qp + 32 * c);
      float4 f1 = *(const float4*)(qp + 32 * c + 4);
      bf16x8 t;
      t[0] = (__bf16)(f0.x * 0.125f); t[1] = (__bf16)(f0.y * 0.125f);
      t[2] = (__bf16)(f0.z * 0.125f); t[3] = (__bf16)(f0.w * 0.125f);
      t[4] = (__bf16)(f1.x * 0.125f); t[5] = (__bf16)(f1.y * 0.125f);
      t[6] = (__bf16)(f1.z * 0.125f); t[7] = (__bf16)(f1.w * 0.125f);
      aq[c] = t;
    }
  }

  float m[4], l[4];
  f32x4 o_acc[4];
  #pragma unroll
  for (int r = 0; r < 4; ++r) { m[r] = -1e30f; l[r] = 0.f; }
  #pragma unroll
  for (int df = 0; df < 4; ++df) o_acc[df] = f32x4{0.f, 0.f, 0.f, 0.f};

  for (int kt = 0; kt < LQ / 64; ++kt) {
    __syncthreads();   // previous tile's LDS reads done before overwrite
    // ---- stage K [key][d] and V^T [d][key] as bf16 ----
    #pragma unroll
    for (int p2 = 0; p2 < 2; ++p2) {
      int idx = tid + p2 * 256;
      int row = idx >> 3;            // key-within-tile 0..63
      int d0 = (idx & 7) * 8;        // dim block
      const float* kp = base + (size_t)(kt * 64 + row) * 1536 + 512 + h * 64 + d0;
      float4 k0 = *(const float4*)kp;
      float4 k1 = *(const float4*)(kp + 4);
      bf16x8 kb;
      kb[0] = (__bf16)k0.x; kb[1] = (__bf16)k0.y; kb[2] = (__bf16)k0.z; kb[3] = (__bf16)k0.w;
      kb[4] = (__bf16)k1.x; kb[5] = (__bf16)k1.y; kb[6] = (__bf16)k1.z; kb[7] = (__bf16)k1.w;
      *(bf16x8*)&Ks[row][d0] = kb;
      const float* vp = kp + 512;
      float4 v0 = *(const float4*)vp;
      float4 v1 = *(const float4*)(vp + 4);
      float vv[8] = {v0.x, v0.y, v0.z, v0.w, v1.x, v1.y, v1.z, v1.w};
      // swizzled col: (row&7) + 8*((row>>3) ^ ((d>>3)&7)); d>>3 const per thread
      int pc = (row & 7) + 8 * ((row >> 3) ^ (d0 >> 3));
      #pragma unroll
      for (int i = 0; i < 8; ++i)
        Vt[d0 + i][pc] = (__bf16)vv[i];
    }
    __syncthreads();

    // ---- S = Q @ K^T : 4 key-frags of 16 ----
    f32x4 s[4];
    #pragma unroll
    for (int f = 0; f < 4; ++f) {
      f32x4 acc = f32x4{0.f, 0.f, 0.f, 0.f};
      #pragma unroll
      for (int c = 0; c < 2; ++c) {
        bf16x8 bk = *(bf16x8*)&Ks[f * 16 + lr][c * 32 + lg * 8];
        acc = __builtin_amdgcn_mfma_f32_16x16x32_bf16(aq[c], bk, acc, 0, 0, 0);
      }
      s[f] = acc;
    }

    // ---- online softmax (rows q = lg*4+r; k spread over lr x 4 frags) ----
    #pragma unroll
    for (int r = 0; r < 4; ++r) {
      float rm = fmaxf(fmaxf(s[0][r], s[1][r]), fmaxf(s[2][r], s[3][r]));
      rm = fmaxf(rm, __shfl_xor(rm, 1));
      rm = fmaxf(rm, __shfl_xor(rm, 2));
      rm = fmaxf(rm, __shfl_xor(rm, 4));
      rm = fmaxf(rm, __shfl_xor(rm, 8));
      float nm = fmaxf(m[r], rm);
      float cor = __expf(m[r] - nm);
      m[r] = nm;
      float rs = 0.f;
      #pragma unroll
      for (int f = 0; f < 4; ++f) {
        float p = __expf(s[f][r] - nm);
        s[f][r] = p;
        rs += p;
      }
      rs += __shfl_xor(rs, 1);
      rs += __shfl_xor(rs, 2);
      rs += __shfl_xor(rs, 4);
      rs += __shfl_xor(rs, 8);
      l[r] = l[r] * cor + rs;
      #pragma unroll
      for (int df = 0; df < 4; ++df) o_acc[df][r] *= cor;
    }

    // ---- P -> per-wave LDS (bf16) ----
    #pragma unroll
    for (int f = 0; f < 4; ++f)
      #pragma unroll
      for (int r = 0; r < 4; ++r)
        Ps[wave][lg * 4 + r][f * 16 + lr] = (__bf16)s[f][r];

    // ---- O += P @ V ----
    #pragma unroll
    for (int kc = 0; kc < 2; ++kc) {
      bf16x8 ap = *(bf16x8*)&Ps[wave][lr][kc * 32 + lg * 8];
      #pragma unroll
      for (int df = 0; df < 4; ++df) {
        int vrow = df * 16 + lr;
        int pb = (((4 * kc + lg) ^ ((vrow >> 3) & 7)) << 3);
        bf16x8 bv = *(bf16x8*)&Vt[vrow][pb];
        o_acc[df] = __builtin_amdgcn_mfma_f32_16x16x32_bf16(ap, bv, o_acc[df], 0, 0, 0);
      }
    }
  }

  // ---- write O ----
  float* orow = o + ((size_t)(b * LQ) + q0 + wave * 16) * DQ + h * 64;
  #pragma unroll
  for (int r = 0; r < 4; ++r) {
    float inv = 1.f / l[r];
    #pragma unroll
    for (int df = 0; df < 4; ++df)
      orow[(size_t)(lg * 4 + r) * DQ + df * 16 + lr] = o_acc[df][r] * inv;
  }
}

// ---------------- LayerNorm over D=512, one block per row ----------------
__global__ __launch_bounds__(256) void ln_kernel(const float* __restrict__ t,
    const float* __restrict__ g, const float* __restrict__ bb, float* __restrict__ xo) {
  int row = blockIdx.x;
  const float* tr = t + (size_t)row * DQ;
  int tid = threadIdx.x;
  float v0 = tr[tid], v1 = tr[tid + 256];
  float s = v0 + v1, ss = v0 * v0 + v1 * v1;
  #pragma unroll
  for (int off = 32; off; off >>= 1) { s += __shfl_xor(s, off); ss += __shfl_xor(ss, off); }
  __shared__ float rs[4], rss[4];
  int w = tid >> 6;
  if ((tid & 63) == 0) { rs[w] = s; rss[w] = ss; }
  __syncthreads();
  s = rs[0] + rs[1] + rs[2] + rs[3];
  ss = rss[0] + rss[1] + rss[2] + rss[3];
  float mean = s * (1.f / 512.f);
  float var = ss * (1.f / 512.f) - mean * mean;
  float r = rsqrtf(var + 1e-5f);
  float* xr = xo + (size_t)row * DQ;
  xr[tid]       = (v0 - mean) * r * g[tid]       + bb[tid];
  xr[tid + 256] = (v1 - mean) * r * g[tid + 256] + bb[tid + 256];
}

// ---------------- start/end logits: one wave per row ----------------
__global__ __launch_bounds__(256) void logits_kernel(const float* __restrict__ hidden,
    const float* __restrict__ sw, const float* __restrict__ sb,
    const float* __restrict__ ew, const float* __restrict__ eb,
    float* __restrict__ osl, float* __restrict__ oel) {
  int row = blockIdx.x * 4 + (threadIdx.x >> 6);
  int lane = threadIdx.x & 63;
  const float* hr = hidden + (size_t)row * DQ;
  float a = 0.f, b2 = 0.f;
  #pragma unroll
  for (int i = 0; i < 8; ++i) {
    int d = lane + i * 64;
    float h = hr[d];
    a += h * sw[d];
    b2 += h * ew[d];
  }
  #pragma unroll
  for (int off = 32; off; off >>= 1) { a += __shfl_xor(a, off); b2 += __shfl_xor(b2, off); }
  if (lane == 0) { osl[row] = a + sb[0]; oel[row] = b2 + eb[0]; }
}

// ---------------- top-5 per (b, which) ----------------
__global__ void topk_kernel(const float* __restrict__ slog, const float* __restrict__ elog,
                            int* __restrict__ sidx, int* __restrict__ eidx) {
  int b = blockIdx.x & 3;
  int which = blockIdx.x >> 2;
  const float* lg = (which ? elog : slog) + (size_t)b * LQ;
  int* outp = (which ? eidx : sidx) + b * KQ;
  int lane = threadIdx.x;
  int ch[KQ];
  for (int k = 0; k < KQ; ++k) {
    float bv = -1e38f; int bi = 1 << 30;
    for (int i = lane; i < LQ; i += 64) {
      bool skip = false;
      for (int t = 0; t < k; ++t) if (ch[t] == i) skip = true;
      float v = lg[i];
      if (!skip && (v > bv || (v == bv && i < bi))) { bv = v; bi = i; }
    }
    #pragma unroll
    for (int off = 32; off; off >>= 1) {
      float ov = __shfl_xor(bv, off); int oi = __shfl_xor(bi, off);
      if (ov > bv || (ov == bv && oi < bi)) { bv = ov; bi = oi; }
    }
    ch[k] = bi;
    if (lane == 0) outp[k] = bi;
  }
}

// ---------------- validity + stable compaction order ----------------
__global__ void vo_kernel(const int* __restrict__ sidx, const int* __restrict__ eidx,
                          int* __restrict__ order, int* __restrict__ vs) {
  int b = threadIdx.x;
  if (b >= BQ) return;
  int val[KQ];
  for (int k = 0; k < KQ; ++k) {
    int s = sidx[b * KQ + k], e = eidx[b * KQ + k];
    val[k] = (e >= s && (e - s) < MAXMQ) ? 1 : 0;
  }
  int j = 0;
  for (int k = 0; k < KQ; ++k) if (val[k])  { order[b * KQ + j] = k; vs[b * KQ + j] = 1; ++j; }
  for (int k = 0; k < KQ; ++k) if (!val[k]) { order[b * KQ + j] = k; vs[b * KQ + j] = 0; ++j; }
}

// ---------------- span features: [h_s, h_e, h_s*h_e] ----------------
__global__ __launch_bounds__(256) void feat_kernel(const float* __restrict__ hidden,
    const int* __restrict__ sidx, const int* __restrict__ eidx, float* __restrict__ feat) {
  int row = blockIdx.x;            // b*K + k
  int b = row / KQ;
  int si = sidx[row], ei = eidx[row];
  const float* hs = hidden + ((size_t)(b * LQ + si)) * DQ;
  const float* he = hidden + ((size_t)(b * LQ + ei)) * DQ;
  float* fr = feat + (size_t)row * (3 * DQ);
  for (int d = threadIdx.x; d < DQ; d += 256) {
    float a = hs[d], c = he[d];
    fr[d] = a; fr[DQ + d] = c; fr[2 * DQ + d] = a * c;
  }
}

// ---------------- compact valid spans to front, zero the rest ----------------
__global__ __launch_bounds__(256) void compact_kernel(const float* __restrict__ spanraw,
    const int* __restrict__ order, const int* __restrict__ vs, float* __restrict__ outspan) {
  int row = blockIdx.x;            // b*K + j
  int b = row / KQ;
  int src = b * KQ + order[row];
  float keep = vs[row] ? 1.f : 0.f;
  for (int d = threadIdx.x; d < DQ; d += 256)
    outspan[(size_t)row * DQ + d] = spanraw[(size_t)src * DQ + d] * keep;
}

// ---------------- scores: (mp @ entity_w) . cand + mp . entity_b ----------------
__global__ __launch_bounds__(256) void scores_kernel(const float* __restrict__ cand,
    const float* __restrict__ mp, const float* __restrict__ u, const float* __restrict__ ebias,
    float* __restrict__ oscores) {
  int gw = blockIdx.x * 4 + (threadIdx.x >> 6);   // (b*K+j)*64 + c
  int lane = threadIdx.x & 63;
  int bj = gw >> 6;
  const float* ce = cand + (size_t)gw * DQ;
  const float* ur = u + (size_t)bj * DQ;
  const float* mr = mp + (size_t)bj * DQ;
  float s = 0.f;
  #pragma unroll
  for (int i = 0; i < 8; ++i) {
    int e = lane + i * 64;
    s += ce[e] * ur[e] + mr[e] * ebias[e];
  }
  #pragma unroll
  for (int off = 32; off; off >>= 1) s += __shfl_xor(s, off);
  if (lane == 0) oscores[gw] = s;
}

extern "C" void kernel_launch(void* const* d_in, const int* in_sizes, int n_in,
                              void* d_out, int out_size, void* d_ws, size_t ws_size,
                              hipStream_t stream) {
  const int*   token_ids = (const int*)d_in[0];
  const float* cand    = (const float*)d_in[1];
  const float* tok_emb = (const float*)d_in[2];
  const float* pos_emb = (const float*)d_in[3];
  const float* ain_w   = (const float*)d_in[4];   // [2,1536,512]
  const float* ain_b   = (const float*)d_in[5];   // [2,1536]
  const float* aout_w  = (const float*)d_in[6];   // [2,512,512]
  const float* aout_b  = (const float*)d_in[7];
  const float* ln1g    = (const float*)d_in[8];
  const float* ln1b    = (const float*)d_in[9];
  const float* fw1     = (const float*)d_in[10];  // [2,2048,512]
  const float* fb1     = (const float*)d_in[11];
  const float* fw2     = (const float*)d_in[12];  // [2,512,2048]
  const float* fb2     = (const float*)d_in[13];
  const float* ln2g    = (const float*)d_in[14];
  const float* ln2b    = (const float*)d_in[15];
  const float* sw      = (const float*)d_in[16];
  const float* sb      = (const float*)d_in[17];
  const float* ew      = (const float*)d_in[18];
  const float* eb      = (const float*)d_in[19];
  const float* sp_w1   = (const float*)d_in[20];  // [512,1536]
  const float* sp_b1   = (const float*)d_in[21];
  const float* sp_w2   = (const float*)d_in[22];  // [512,512]
  const float* sp_b2   = (const float*)d_in[23];
  const float* m_w     = (const float*)d_in[24];
  const float* m_b     = (const float*)d_in[25];
  const float* e_w     = (const float*)d_in[26];
  const float* e_b     = (const float*)d_in[27];

  const int M = BQ * LQ;           // 8192
  float* out = (float*)d_out;
  float* out_span   = out;                  // [4,5,512]   = 10240
  float* out_sl     = out + 10240;          // [4,2048]    = 8192
  float* out_el     = out + 18432;          // [4,2048]    = 8192
  float* out_hidden = out + 26624;          // [4,2048,512]= 4194304
  float* out_scores = out + 4220928;        // [4,5,64]    = 1280

  float* ws  = (float*)d_ws;
  float* X   = ws;                          // [8192,512]
  float* T   = ws + 4194304;                // [8192,512]
  float* O   = ws + 8388608;                // [8192,512]
  float* BIG = ws + 12582912;               // [8192,2048] (qkv uses [8192,1536])
  int*   SIDX  = (int*)(ws + 29360128);     // 20
  int*   EIDX  = SIDX + 20;
  int*   ORDER = EIDX + 20;
  int*   VS    = ORDER + 20;
  float* FEAT    = ws + 29360208;           // [20,1536]
  float* SPANH   = FEAT + 20 * 1536;        // [20,512]
  float* SPANRAW = SPANH + 10240;           // [20,512]
  float* MP      = SPANRAW + 10240;         // [20,512]
  float* U       = MP + 10240;              // [20,512]

  embed_kernel<<<M, 256, 0, stream>>>(token_ids, tok_emb, pos_emb, X);

  for (int l = 0; l < 2; ++l) {
    // qkv = x @ in_w^T + in_b
    gemm_kernel<true, false, false><<<dim3(24, 128), 256, 0, stream>>>(
        X, ain_w + (size_t)l * 1536 * 512, ain_b + l * 1536, nullptr, BIG, M, 1536, 512);
    // attention (MFMA flash)
    attn_mfma_kernel<<<dim3(LQ / 64, BQ * HQ), 256, 0, stream>>>(BIG, O);
    // t = x + o @ out_w^T + out_b
    gemm_kernel<true, false, true><<<dim3(8, 128), 256, 0, stream>>>(
        O, aout_w + (size_t)l * 512 * 512, aout_b + l * 512, X, T, M, 512, 512);
    ln_kernel<<<M, 256, 0, stream>>>(T, ln1g + l * 512, ln1b + l * 512, X);
    // ffn
    gemm_kernel<true, true, false><<<dim3(32, 128), 256, 0, stream>>>(
        X, fw1 + (size_t)l * 2048 * 512, fb1 + l * 2048, nullptr, BIG, M, 2048, 512);
    gemm_kernel<true, false, true><<<dim3(8, 128), 256, 0, stream>>>(
        BIG, fw2 + (size_t)l * 512 * 2048, fb2 + l * 512, X, T, M, 512, 2048);
    ln_kernel<<<M, 256, 0, stream>>>(T, ln2g + l * 512, ln2b + l * 512, X);
  }

  // heads
  logits_kernel<<<M / 4, 256, 0, stream>>>(X, sw, sb, ew, eb, out_sl, out_el);
  topk_kernel<<<8, 64, 0, stream>>>(out_sl, out_el, SIDX, EIDX);
  vo_kernel<<<1, 64, 0, stream>>>(SIDX, EIDX, ORDER, VS);
  feat_kernel<<<20, 256, 0, stream>>>(X, SIDX, EIDX, FEAT);
  gemm_kernel<true, true, false><<<dim3(8, 1), 256, 0, stream>>>(
      FEAT, sp_w1, sp_b1, nullptr, SPANH, 20, 512, 1536);
  gemm_kernel<true, false, false><<<dim3(8, 1), 256, 0, stream>>>(
      SPANH, sp_w2, sp_b2, nullptr, SPANRAW, 20, 512, 512);
  compact_kernel<<<20, 256, 0, stream>>>(SPANRAW, ORDER, VS, out_span);
  gemm_kernel<true, false, false><<<dim3(8, 1), 256, 0, stream>>>(
      out_span, m_w, m_b, nullptr, MP, 20, 512, 512);
  // u = mp @ entity_w  (W not transposed)
  gemm_kernel<false, false, false><<<dim3(8, 1), 256, 0, stream>>>(
      MP, e_w, nullptr, nullptr, U, 20, 512, 512);
  scores_kernel<<<320, 256, 0, stream>>>(cand, MP, U, e_b, out_scores);

  // hidden output (f32 copy)
  hipMemcpyAsync(out_hidden, X, (size_t)M * DQ * sizeof(float),
                 hipMemcpyDeviceToDevice, stream);
}

// Round 3
// 1077.023 us; speedup vs baseline: 20.1701x; 5.2526x over previous
//
#include <hip/hip_runtime.h>
#include <hip/hip_bf16.h>
#include <cstddef>

#define BQ 4
#define LQ 2048
#define DQ 512
#define HQ 8
#define HDQ 64
#define KQ 5
#define MAXMQ 10

typedef __attribute__((ext_vector_type(8))) __bf16 bf16x8;
typedef __attribute__((ext_vector_type(4))) float f32x4;

__device__ inline void gload_lds16(const void* g, void* l) {
  __builtin_amdgcn_global_load_lds(
      (const __attribute__((address_space(1))) unsigned*)g,
      (__attribute__((address_space(3))) unsigned*)l, 16, 0, 0);
}

// ---------------- f32 -> bf16 weight conversion ----------------
__global__ __launch_bounds__(256) void cvt_kernel(const float* __restrict__ in,
                                                  __bf16* __restrict__ out, int n) {
  for (int i = (blockIdx.x * 256 + threadIdx.x) * 8; i < n; i += gridDim.x * 256 * 8) {
    float4 a = *(const float4*)(in + i);
    float4 b = *(const float4*)(in + i + 4);
    bf16x8 t;
    t[0] = (__bf16)a.x; t[1] = (__bf16)a.y; t[2] = (__bf16)a.z; t[3] = (__bf16)a.w;
    t[4] = (__bf16)b.x; t[5] = (__bf16)b.y; t[6] = (__bf16)b.z; t[7] = (__bf16)b.w;
    *(bf16x8*)(out + i) = t;
  }
}

// ---------------- embedding: x = tok_emb[ids] + pos_emb (f32 + bf16) ----------------
__global__ __launch_bounds__(256) void embed_kernel(const int* __restrict__ tok,
    const float* __restrict__ te, const float* __restrict__ pe,
    float* __restrict__ x, __bf16* __restrict__ xb) {
  int row = blockIdx.x;              // b*L + l
  int l = row & (LQ - 1);
  int t = tok[row];
  const float* trow = te + (size_t)t * DQ;
  const float* prow = pe + (size_t)l * DQ;
  float* xr = x + (size_t)row * DQ;
  __bf16* xbr = xb + (size_t)row * DQ;
  for (int d = threadIdx.x; d < DQ; d += 256) {
    float v = trow[d] + prow[d];
    xr[d] = v;
    xbr[d] = (__bf16)v;
  }
}

// ---------------- bf16 MFMA GEMM (m97 structure): C = act(A @ W^T + bias + R) ----
// A:[M,K] bf16 row-major, W:[N,K] bf16 row-major. 128x128 tile, BK=32, 4 waves.
// M,N multiples of 128; K multiple of 32.
template<bool RELU, bool HASRES, bool WF32, bool WBF16>
__global__ __launch_bounds__(256) void bgemm_kernel(
    const __bf16* __restrict__ A, const __bf16* __restrict__ W,
    const float* __restrict__ bias, const float* __restrict__ R,
    float* __restrict__ C, __bf16* __restrict__ Cb, int M, int N, int K) {
  __shared__ __bf16 As[128][32];
  __shared__ __bf16 Bs[128][32];
  const int tid = threadIdx.x;
  const int w = tid >> 6, lane = tid & 63;
  const int lr = lane & 15, lg = lane >> 4;
  const int wr = w >> 1, wc = w & 1;
  const int m0 = blockIdx.y * 128, n0 = blockIdx.x * 128;

  f32x4 acc[4][4];
  #pragma unroll
  for (int m = 0; m < 4; ++m)
    #pragma unroll
    for (int n = 0; n < 4; ++n) acc[m][n] = f32x4{0.f, 0.f, 0.f, 0.f};

  // staging address: wave w covers tile rows w*32 + s*16 + (lane>>2), cols (lane&3)*8
  const int srow = w * 32 + (lane >> 2);
  const int scol = (lane & 3) * 8;
  const __bf16* Ag = A + (size_t)(m0 + srow) * K + scol;
  const __bf16* Bg = W + (size_t)(n0 + srow) * K + scol;

  for (int k0 = 0; k0 < K; k0 += 32) {
    gload_lds16(Ag + k0,            &As[w * 32][0]);
    gload_lds16(Ag + 16 * K + k0,   &As[w * 32 + 16][0]);
    gload_lds16(Bg + k0,            &Bs[w * 32][0]);
    gload_lds16(Bg + 16 * K + k0,   &Bs[w * 32 + 16][0]);
    __syncthreads();
    bf16x8 af[4], bfr[4];
    #pragma unroll
    for (int m = 0; m < 4; ++m) af[m] = *(bf16x8*)&As[wr * 64 + m * 16 + lr][lg * 8];
    #pragma unroll
    for (int n = 0; n < 4; ++n) bfr[n] = *(bf16x8*)&Bs[wc * 64 + n * 16 + lr][lg * 8];
    #pragma unroll
    for (int m = 0; m < 4; ++m)
      #pragma unroll
      for (int n = 0; n < 4; ++n)
        acc[m][n] = __builtin_amdgcn_mfma_f32_16x16x32_bf16(af[m], bfr[n], acc[m][n], 0, 0, 0);
    __syncthreads();
  }

  // epilogue: C/D layout row=(lane>>4)*4+reg, col=lane&15
  const int crow = m0 + wr * 64 + lg * 4;
  const int ccol = n0 + wc * 64 + lr;
  #pragma unroll
  for (int n = 0; n < 4; ++n) {
    int gc = ccol + n * 16;
    float bn = bias ? bias[gc] : 0.f;
    #pragma unroll
    for (int m = 0; m < 4; ++m) {
      #pragma unroll
      for (int reg = 0; reg < 4; ++reg) {
        int gr = crow + m * 16 + reg;
        float v = acc[m][n][reg] + bn;
        if (HASRES) v += R[(size_t)gr * N + gc];
        if (RELU) v = fmaxf(v, 0.f);
        if (WF32) C[(size_t)gr * N + gc] = v;
        if (WBF16) Cb[(size_t)gr * N + gc] = (__bf16)v;
      }
    }
  }
}

// ---------------- generic small f32 GEMM (span head etc.) ----------------
template<bool WT, bool RELU, bool HASRES>
__global__ __launch_bounds__(256) void gemm_kernel(
    const float* __restrict__ A, const float* __restrict__ W,
    const float* __restrict__ bias, const float* __restrict__ R,
    float* __restrict__ C, int M, int N, int Kd) {
  __shared__ float As[64][36];
  __shared__ float Ws[64][36];
  int tid = threadIdx.x;
  int tx = tid & 15, ty = tid >> 4;
  int m0 = blockIdx.y * 64, n0 = blockIdx.x * 64;
  float acc[4][4] = {};
  for (int k0 = 0; k0 < Kd; k0 += 32) {
    #pragma unroll
    for (int i = 0; i < 8; ++i) {
      int idx = tid + i * 256;
      int r = idx >> 5, c = idx & 31;
      int gm = m0 + r;
      As[r][c] = (gm < M) ? A[(size_t)gm * Kd + k0 + c] : 0.f;
    }
    #pragma unroll
    for (int i = 0; i < 8; ++i) {
      int idx = tid + i * 256;
      int r = idx >> 5, c = idx & 31;
      int gn = n0 + r;
      float wv = 0.f;
      if (gn < N) wv = WT ? W[(size_t)gn * Kd + k0 + c] : W[(size_t)(k0 + c) * N + gn];
      Ws[r][c] = wv;
    }
    __syncthreads();
    #pragma unroll
    for (int kk = 0; kk < 32; kk += 4) {
      float4 a[4], w[4];
      #pragma unroll
      for (int i = 0; i < 4; ++i) a[i] = *(const float4*)&As[ty * 4 + i][kk];
      #pragma unroll
      for (int j = 0; j < 4; ++j) w[j] = *(const float4*)&Ws[tx * 4 + j][kk];
      #pragma unroll
      for (int i = 0; i < 4; ++i)
        #pragma unroll
        for (int j = 0; j < 4; ++j)
          acc[i][j] += a[i].x * w[j].x + a[i].y * w[j].y + a[i].z * w[j].z + a[i].w * w[j].w;
    }
    __syncthreads();
  }
  #pragma unroll
  for (int i = 0; i < 4; ++i) {
    int gm = m0 + ty * 4 + i;
    if (gm >= M) continue;
    #pragma unroll
    for (int j = 0; j < 4; ++j) {
      int gn = n0 + tx * 4 + j;
      float v = acc[i][j];
      if (bias) v += bias[gn];
      if (HASRES) v += R[(size_t)gm * N + gn];
      if (RELU) v = fmaxf(v, 0.f);
      C[(size_t)gm * N + gn] = v;
    }
  }
}

// ---------------- MFMA flash attention (bf16 qkv in, bf16 O out) ----------------
// Block: 4 waves; one (b,h), 64 query rows (16 per wave). scale folded post-MFMA.
__global__ __launch_bounds__(256) void attn_mfma_kernel(const __bf16* __restrict__ qkv,
                                                        __bf16* __restrict__ ob) {
  __shared__ __bf16 Ks[64][72];       // [key][d]
  __shared__ __bf16 Vt[64][72];       // [d][key], col-block XOR swizzled
  __shared__ __bf16 Ps[4][16][72];    // per-wave P tile [q][key]

  const int tid = threadIdx.x;
  const int wave = tid >> 6;
  const int lane = tid & 63;
  const int lr = lane & 15;
  const int lg = lane >> 4;
  const int bh = blockIdx.y;
  const int b = bh >> 3, h = bh & 7;
  const int q0 = blockIdx.x * 64;

  const __bf16* base = qkv + (size_t)b * LQ * 1536;

  bf16x8 aq[2];
  {
    const int qrow = q0 + wave * 16 + lr;
    const __bf16* qp = base + (size_t)qrow * 1536 + h * 64 + lg * 8;
    aq[0] = *(const bf16x8*)qp;
    aq[1] = *(const bf16x8*)(qp + 32);
  }

  float m[4], l[4];
  f32x4 o_acc[4];
  #pragma unroll
  for (int r = 0; r < 4; ++r) { m[r] = -1e30f; l[r] = 0.f; }
  #pragma unroll
  for (int df = 0; df < 4; ++df) o_acc[df] = f32x4{0.f, 0.f, 0.f, 0.f};

  for (int kt = 0; kt < LQ / 64; ++kt) {
    __syncthreads();
    #pragma unroll
    for (int p2 = 0; p2 < 2; ++p2) {
      int idx = tid + p2 * 256;
      int row = idx >> 3;            // key 0..63
      int d0 = (idx & 7) * 8;        // dim block
      const __bf16* kp = base + (size_t)(kt * 64 + row) * 1536 + 512 + h * 64 + d0;
      *(bf16x8*)&Ks[row][d0] = *(const bf16x8*)kp;
      bf16x8 vb = *(const bf16x8*)(kp + 512);
      int pc = (row & 7) + 8 * ((row >> 3) ^ (d0 >> 3));
      #pragma unroll
      for (int i = 0; i < 8; ++i)
        Vt[d0 + i][pc] = vb[i];
    }
    __syncthreads();

    // S = Q @ K^T, then scale by 1/sqrt(64)
    f32x4 s[4];
    #pragma unroll
    for (int f = 0; f < 4; ++f) {
      f32x4 acc = f32x4{0.f, 0.f, 0.f, 0.f};
      #pragma unroll
      for (int c = 0; c < 2; ++c) {
        bf16x8 bk = *(bf16x8*)&Ks[f * 16 + lr][c * 32 + lg * 8];
        acc = __builtin_amdgcn_mfma_f32_16x16x32_bf16(aq[c], bk, acc, 0, 0, 0);
      }
      s[f] = acc * 0.125f;
    }

    #pragma unroll
    for (int r = 0; r < 4; ++r) {
      float rm = fmaxf(fmaxf(s[0][r], s[1][r]), fmaxf(s[2][r], s[3][r]));
      rm = fmaxf(rm, __shfl_xor(rm, 1));
      rm = fmaxf(rm, __shfl_xor(rm, 2));
      rm = fmaxf(rm, __shfl_xor(rm, 4));
      rm = fmaxf(rm, __shfl_xor(rm, 8));
      float nm = fmaxf(m[r], rm);
      float cor = __expf(m[r] - nm);
      m[r] = nm;
      float rs = 0.f;
      #pragma unroll
      for (int f = 0; f < 4; ++f) {
        float p = __expf(s[f][r] - nm);
        s[f][r] = p;
        rs += p;
      }
      rs += __shfl_xor(rs, 1);
      rs += __shfl_xor(rs, 2);
      rs += __shfl_xor(rs, 4);
      rs += __shfl_xor(rs, 8);
      l[r] = l[r] * cor + rs;
      #pragma unroll
      for (int df = 0; df < 4; ++df) o_acc[df][r] *= cor;
    }

    #pragma unroll
    for (int f = 0; f < 4; ++f)
      #pragma unroll
      for (int r = 0; r < 4; ++r)
        Ps[wave][lg * 4 + r][f * 16 + lr] = (__bf16)s[f][r];

    #pragma unroll
    for (int kc = 0; kc < 2; ++kc) {
      bf16x8 ap = *(bf16x8*)&Ps[wave][lr][kc * 32 + lg * 8];
      #pragma unroll
      for (int df = 0; df < 4; ++df) {
        int vrow = df * 16 + lr;
        int pb = (((4 * kc + lg) ^ ((vrow >> 3) & 7)) << 3);
        bf16x8 bv = *(bf16x8*)&Vt[vrow][pb];
        o_acc[df] = __builtin_amdgcn_mfma_f32_16x16x32_bf16(ap, bv, o_acc[df], 0, 0, 0);
      }
    }
  }

  __bf16* orow = ob + ((size_t)(b * LQ) + q0 + wave * 16) * DQ + h * 64;
  #pragma unroll
  for (int r = 0; r < 4; ++r) {
    float inv = 1.f / l[r];
    #pragma unroll
    for (int df = 0; df < 4; ++df)
      orow[(size_t)(lg * 4 + r) * DQ + df * 16 + lr] = (__bf16)(o_acc[df][r] * inv);
  }
}

// ---------------- LayerNorm over D=512 (writes f32 + bf16) ----------------
__global__ __launch_bounds__(256) void ln_kernel(const float* __restrict__ t,
    const float* __restrict__ g, const float* __restrict__ bb,
    float* __restrict__ xo, __bf16* __restrict__ xb) {
  int row = blockIdx.x;
  const float* tr = t + (size_t)row * DQ;
  int tid = threadIdx.x;
  float v0 = tr[tid], v1 = tr[tid + 256];
  float s = v0 + v1, ss = v0 * v0 + v1 * v1;
  #pragma unroll
  for (int off = 32; off; off >>= 1) { s += __shfl_xor(s, off); ss += __shfl_xor(ss, off); }
  __shared__ float rs[4], rss[4];
  int w = tid >> 6;
  if ((tid & 63) == 0) { rs[w] = s; rss[w] = ss; }
  __syncthreads();
  s = rs[0] + rs[1] + rs[2] + rs[3];
  ss = rss[0] + rss[1] + rss[2] + rss[3];
  float mean = s * (1.f / 512.f);
  float var = ss * (1.f / 512.f) - mean * mean;
  float r = rsqrtf(var + 1e-5f);
  float* xr = xo + (size_t)row * DQ;
  __bf16* xbr = xb + (size_t)row * DQ;
  float o0 = (v0 - mean) * r * g[tid] + bb[tid];
  float o1 = (v1 - mean) * r * g[tid + 256] + bb[tid + 256];
  xr[tid] = o0; xr[tid + 256] = o1;
  xbr[tid] = (__bf16)o0; xbr[tid + 256] = (__bf16)o1;
}

// ---------------- start/end logits ----------------
__global__ __launch_bounds__(256) void logits_kernel(const float* __restrict__ hidden,
    const float* __restrict__ sw, const float* __restrict__ sb,
    const float* __restrict__ ew, const float* __restrict__ eb,
    float* __restrict__ osl, float* __restrict__ oel) {
  int row = blockIdx.x * 4 + (threadIdx.x >> 6);
  int lane = threadIdx.x & 63;
  const float* hr = hidden + (size_t)row * DQ;
  float a = 0.f, b2 = 0.f;
  #pragma unroll
  for (int i = 0; i < 8; ++i) {
    int d = lane + i * 64;
    float h = hr[d];
    a += h * sw[d];
    b2 += h * ew[d];
  }
  #pragma unroll
  for (int off = 32; off; off >>= 1) { a += __shfl_xor(a, off); b2 += __shfl_xor(b2, off); }
  if (lane == 0) { osl[row] = a + sb[0]; oel[row] = b2 + eb[0]; }
}

// ---------------- top-5 per (b, which) ----------------
__global__ void topk_kernel(const float* __restrict__ slog, const float* __restrict__ elog,
                            int* __restrict__ sidx, int* __restrict__ eidx) {
  int b = blockIdx.x & 3;
  int which = blockIdx.x >> 2;
  const float* lg = (which ? elog : slog) + (size_t)b * LQ;
  int* outp = (which ? eidx : sidx) + b * KQ;
  int lane = threadIdx.x;
  int ch[KQ];
  for (int k = 0; k < KQ; ++k) {
    float bv = -1e38f; int bi = 1 << 30;
    for (int i = lane; i < LQ; i += 64) {
      bool skip = false;
      for (int t = 0; t < k; ++t) if (ch[t] == i) skip = true;
      float v = lg[i];
      if (!skip && (v > bv || (v == bv && i < bi))) { bv = v; bi = i; }
    }
    #pragma unroll
    for (int off = 32; off; off >>= 1) {
      float ov = __shfl_xor(bv, off); int oi = __shfl_xor(bi, off);
      if (ov > bv || (ov == bv && oi < bi)) { bv = ov; bi = oi; }
    }
    ch[k] = bi;
    if (lane == 0) outp[k] = bi;
  }
}

// ---------------- validity + stable compaction order ----------------
__global__ void vo_kernel(const int* __restrict__ sidx, const int* __restrict__ eidx,
                          int* __restrict__ order, int* __restrict__ vs) {
  int b = threadIdx.x;
  if (b >= BQ) return;
  int val[KQ];
  for (int k = 0; k < KQ; ++k) {
    int s = sidx[b * KQ + k], e = eidx[b * KQ + k];
    val[k] = (e >= s && (e - s) < MAXMQ) ? 1 : 0;
  }
  int j = 0;
  for (int k = 0; k < KQ; ++k) if (val[k])  { order[b * KQ + j] = k; vs[b * KQ + j] = 1; ++j; }
  for (int k = 0; k < KQ; ++k) if (!val[k]) { order[b * KQ + j] = k; vs[b * KQ + j] = 0; ++j; }
}

// ---------------- span features ----------------
__global__ __launch_bounds__(256) void feat_kernel(const float* __restrict__ hidden,
    const int* __restrict__ sidx, const int* __restrict__ eidx, float* __restrict__ feat) {
  int row = blockIdx.x;            // b*K + k
  int b = row / KQ;
  int si = sidx[row], ei = eidx[row];
  const float* hs = hidden + ((size_t)(b * LQ + si)) * DQ;
  const float* he = hidden + ((size_t)(b * LQ + ei)) * DQ;
  float* fr = feat + (size_t)row * (3 * DQ);
  for (int d = threadIdx.x; d < DQ; d += 256) {
    float a = hs[d], c = he[d];
    fr[d] = a; fr[DQ + d] = c; fr[2 * DQ + d] = a * c;
  }
}

// ---------------- compact valid spans to front, zero the rest ----------------
__global__ __launch_bounds__(256) void compact_kernel(const float* __restrict__ spanraw,
    const int* __restrict__ order, const int* __restrict__ vs, float* __restrict__ outspan) {
  int row = blockIdx.x;            // b*K + j
  int b = row / KQ;
  int src = b * KQ + order[row];
  float keep = vs[row] ? 1.f : 0.f;
  for (int d = threadIdx.x; d < DQ; d += 256)
    outspan[(size_t)row * DQ + d] = spanraw[(size_t)src * DQ + d] * keep;
}

// ---------------- scores ----------------
__global__ __launch_bounds__(256) void scores_kernel(const float* __restrict__ cand,
    const float* __restrict__ mp, const float* __restrict__ u, const float* __restrict__ ebias,
    float* __restrict__ oscores) {
  int gw = blockIdx.x * 4 + (threadIdx.x >> 6);   // (b*K+j)*64 + c
  int lane = threadIdx.x & 63;
  int bj = gw >> 6;
  const float* ce = cand + (size_t)gw * DQ;
  const float* ur = u + (size_t)bj * DQ;
  const float* mr = mp + (size_t)bj * DQ;
  float s = 0.f;
  #pragma unroll
  for (int i = 0; i < 8; ++i) {
    int e = lane + i * 64;
    s += ce[e] * ur[e] + mr[e] * ebias[e];
  }
  #pragma unroll
  for (int off = 32; off; off >>= 1) s += __shfl_xor(s, off);
  if (lane == 0) oscores[gw] = s;
}

extern "C" void kernel_launch(void* const* d_in, const int* in_sizes, int n_in,
                              void* d_out, int out_size, void* d_ws, size_t ws_size,
                              hipStream_t stream) {
  const int*   token_ids = (const int*)d_in[0];
  const float* cand    = (const float*)d_in[1];
  const float* tok_emb = (const float*)d_in[2];
  const float* pos_emb = (const float*)d_in[3];
  const float* ain_w   = (const float*)d_in[4];   // [2,1536,512]
  const float* ain_b   = (const float*)d_in[5];
  const float* aout_w  = (const float*)d_in[6];   // [2,512,512]
  const float* aout_b  = (const float*)d_in[7];
  const float* ln1g    = (const float*)d_in[8];
  const float* ln1b    = (const float*)d_in[9];
  const float* fw1     = (const float*)d_in[10];  // [2,2048,512]
  const float* fb1     = (const float*)d_in[11];
  const float* fw2     = (const float*)d_in[12];  // [2,512,2048]
  const float* fb2     = (const float*)d_in[13];
  const float* ln2g    = (const float*)d_in[14];
  const float* ln2b    = (const float*)d_in[15];
  const float* sw      = (const float*)d_in[16];
  const float* sb      = (const float*)d_in[17];
  const float* ew      = (const float*)d_in[18];
  const float* eb      = (const float*)d_in[19];
  const float* sp_w1   = (const float*)d_in[20];  // [512,1536]
  const float* sp_b1   = (const float*)d_in[21];
  const float* sp_w2   = (const float*)d_in[22];  // [512,512]
  const float* sp_b2   = (const float*)d_in[23];
  const float* m_w     = (const float*)d_in[24];
  const float* m_b     = (const float*)d_in[25];
  const float* e_w     = (const float*)d_in[26];
  const float* e_b     = (const float*)d_in[27];

  const int M = BQ * LQ;           // 8192
  float* out = (float*)d_out;
  float* out_span   = out;                  // [4,5,512]
  float* out_sl     = out + 10240;          // [4,2048]
  float* out_el     = out + 18432;          // [4,2048]
  float* out_hidden = out + 26624;          // [4,2048,512]
  float* out_scores = out + 4220928;        // [4,5,64]

  float* ws  = (float*)d_ws;
  float* X    = ws;                               // f32 [8192,512]
  float* T    = ws + 4194304;                     // f32 [8192,512]
  __bf16* BIGb = (__bf16*)(ws + 8388608);         // bf16 [8192,2048] (qkv uses 1536)
  __bf16* Xb   = (__bf16*)(ws + 16777216);        // bf16 [8192,512]
  __bf16* Ob   = (__bf16*)(ws + 18874368);        // bf16 [8192,512]
  __bf16* ain_wb  = (__bf16*)(ws + 20971520);     // 2*1536*512
  __bf16* aout_wb = (__bf16*)(ws + 21757952);     // 2*512*512
  __bf16* fw1b    = (__bf16*)(ws + 22020096);     // 2*2048*512
  __bf16* fw2b    = (__bf16*)(ws + 23068672);     // 2*512*2048
  int*   SIDX  = (int*)(ws + 29360128);
  int*   EIDX  = SIDX + 20;
  int*   ORDER = EIDX + 20;
  int*   VS    = ORDER + 20;
  float* FEAT    = ws + 29360208;                 // [20,1536]
  float* SPANH   = FEAT + 20 * 1536;
  float* SPANRAW = SPANH + 10240;
  float* MP      = SPANRAW + 10240;
  float* U       = MP + 10240;

  // weight conversion (bf16)
  cvt_kernel<<<768, 256, 0, stream>>>(ain_w,  ain_wb,  2 * 1536 * 512);
  cvt_kernel<<<256, 256, 0, stream>>>(aout_w, aout_wb, 2 * 512 * 512);
  cvt_kernel<<<1024, 256, 0, stream>>>(fw1,   fw1b,    2 * 2048 * 512);
  cvt_kernel<<<1024, 256, 0, stream>>>(fw2,   fw2b,    2 * 512 * 2048);

  embed_kernel<<<M, 256, 0, stream>>>(token_ids, tok_emb, pos_emb, X, Xb);

  for (int l = 0; l < 2; ++l) {
    // qkv = x @ in_w^T + in_b  -> bf16
    bgemm_kernel<false, false, false, true><<<dim3(12, 64), 256, 0, stream>>>(
        Xb, ain_wb + (size_t)l * 1536 * 512, ain_b + l * 1536, nullptr,
        nullptr, BIGb, M, 1536, 512);
    // attention (MFMA flash, bf16 in/out)
    attn_mfma_kernel<<<dim3(LQ / 64, BQ * HQ), 256, 0, stream>>>(BIGb, Ob);
    // t = x + o @ out_w^T + out_b  -> f32
    bgemm_kernel<false, true, true, false><<<dim3(4, 64), 256, 0, stream>>>(
        Ob, aout_wb + (size_t)l * 512 * 512, aout_b + l * 512, X,
        T, nullptr, M, 512, 512);
    ln_kernel<<<M, 256, 0, stream>>>(T, ln1g + l * 512, ln1b + l * 512, X, Xb);
    // ffn1: relu(x @ w1^T + b1) -> bf16
    bgemm_kernel<true, false, false, true><<<dim3(16, 64), 256, 0, stream>>>(
        Xb, fw1b + (size_t)l * 2048 * 512, fb1 + l * 2048, nullptr,
        nullptr, BIGb, M, 2048, 512);
    // ffn2: x + h @ w2^T + b2 -> f32
    bgemm_kernel<false, true, true, false><<<dim3(4, 64), 256, 0, stream>>>(
        BIGb, fw2b + (size_t)l * 512 * 2048, fb2 + l * 512, X,
        T, nullptr, M, 512, 2048);
    ln_kernel<<<M, 256, 0, stream>>>(T, ln2g + l * 512, ln2b + l * 512, X, Xb);
  }

  // heads
  logits_kernel<<<M / 4, 256, 0, stream>>>(X, sw, sb, ew, eb, out_sl, out_el);
  topk_kernel<<<8, 64, 0, stream>>>(out_sl, out_el, SIDX, EIDX);
  vo_kernel<<<1, 64, 0, stream>>>(SIDX, EIDX, ORDER, VS);
  feat_kernel<<<20, 256, 0, stream>>>(X, SIDX, EIDX, FEAT);
  gemm_kernel<true, true, false><<<dim3(8, 1), 256, 0, stream>>>(
      FEAT, sp_w1, sp_b1, nullptr, SPANH, 20, 512, 1536);
  gemm_kernel<true, false, false><<<dim3(8, 1), 256, 0, stream>>>(
      SPANH, sp_w2, sp_b2, nullptr, SPANRAW, 20, 512, 512);
  compact_kernel<<<20, 256, 0, stream>>>(SPANRAW, ORDER, VS, out_span);
  gemm_kernel<true, false, false><<<dim3(8, 1), 256, 0, stream>>>(
      out_span, m_w, m_b, nullptr, MP, 20, 512, 512);
  gemm_kernel<false, false, false><<<dim3(8, 1), 256, 0, stream>>>(
      MP, e_w, nullptr, nullptr, U, 20, 512, 512);
  scores_kernel<<<320, 256, 0, stream>>>(cand, MP, U, e_b, out_scores);

  hipMemcpyAsync(out_hidden, X, (size_t)M * DQ * sizeof(float),
                 hipMemcpyDeviceToDevice, stream);
}

// Round 4
// 640.247 us; speedup vs baseline: 33.9301x; 1.6822x over previous
//
#include <hip/hip_runtime.h>
#include <hip/hip_bf16.h>
#include <cstddef>

#define BQ 4
#define LQ 2048
#define DQ 512
#define HQ 8
#define HDQ 64
#define KQ 5
#define MAXMQ 10

typedef __attribute__((ext_vector_type(8))) __bf16 bf16x8;
typedef __attribute__((ext_vector_type(4))) float f32x4;

__device__ inline void gload_lds16(const void* g, void* l) {
  __builtin_amdgcn_global_load_lds(
      (const __attribute__((address_space(1))) unsigned*)g,
      (__attribute__((address_space(3))) unsigned*)l, 16, 0, 0);
}

// ---------------- f32 -> bf16 weight conversion ----------------
__global__ __launch_bounds__(256) void cvt_kernel(const float* __restrict__ in,
                                                  __bf16* __restrict__ out, int n) {
  for (int i = (blockIdx.x * 256 + threadIdx.x) * 8; i < n; i += gridDim.x * 256 * 8) {
    float4 a = *(const float4*)(in + i);
    float4 b = *(const float4*)(in + i + 4);
    bf16x8 t;
    t[0] = (__bf16)a.x; t[1] = (__bf16)a.y; t[2] = (__bf16)a.z; t[3] = (__bf16)a.w;
    t[4] = (__bf16)b.x; t[5] = (__bf16)b.y; t[6] = (__bf16)b.z; t[7] = (__bf16)b.w;
    *(bf16x8*)(out + i) = t;
  }
}

// ---------------- 512x512 f32 transpose (entity_w) ----------------
__global__ __launch_bounds__(256) void transpose512_kernel(const float* __restrict__ in,
                                                           float* __restrict__ out) {
  __shared__ float t[32][33];
  int bx = blockIdx.x & 15, by = blockIdx.x >> 4;
  int cx = threadIdx.x & 31, ry = threadIdx.x >> 5;   // 32 x 8
  #pragma unroll
  for (int i = 0; i < 4; ++i)
    t[ry + i * 8][cx] = in[(size_t)(by * 32 + ry + i * 8) * 512 + bx * 32 + cx];
  __syncthreads();
  #pragma unroll
  for (int i = 0; i < 4; ++i)
    out[(size_t)(bx * 32 + ry + i * 8) * 512 + by * 32 + cx] = t[cx][ry + i * 8];
}

// ---------------- embedding: x = tok_emb[ids] + pos_emb (f32 + bf16) ----------------
__global__ __launch_bounds__(256) void embed_kernel(const int* __restrict__ tok,
    const float* __restrict__ te, const float* __restrict__ pe,
    float* __restrict__ x, __bf16* __restrict__ xb) {
  int row = blockIdx.x;              // b*L + l
  int l = row & (LQ - 1);
  int t = tok[row];
  const float* trow = te + (size_t)t * DQ;
  const float* prow = pe + (size_t)l * DQ;
  float* xr = x + (size_t)row * DQ;
  __bf16* xbr = xb + (size_t)row * DQ;
  for (int d = threadIdx.x; d < DQ; d += 256) {
    float v = trow[d] + prow[d];
    xr[d] = v;
    xbr[d] = (__bf16)v;
  }
}

// ---------------- bf16 MFMA GEMM (m97 structure): C = act(A @ W^T + bias + R) ----
template<bool RELU, bool HASRES, bool WF32, bool WBF16>
__global__ __launch_bounds__(256) void bgemm_kernel(
    const __bf16* __restrict__ A, const __bf16* __restrict__ W,
    const float* __restrict__ bias, const float* __restrict__ R,
    float* __restrict__ C, __bf16* __restrict__ Cb, int M, int N, int K) {
  __shared__ __bf16 As[128][32];
  __shared__ __bf16 Bs[128][32];
  const int tid = threadIdx.x;
  const int w = tid >> 6, lane = tid & 63;
  const int lr = lane & 15, lg = lane >> 4;
  const int wr = w >> 1, wc = w & 1;
  const int m0 = blockIdx.y * 128, n0 = blockIdx.x * 128;

  f32x4 acc[4][4];
  #pragma unroll
  for (int m = 0; m < 4; ++m)
    #pragma unroll
    for (int n = 0; n < 4; ++n) acc[m][n] = f32x4{0.f, 0.f, 0.f, 0.f};

  const int srow = w * 32 + (lane >> 2);
  const int scol = (lane & 3) * 8;
  const __bf16* Ag = A + (size_t)(m0 + srow) * K + scol;
  const __bf16* Bg = W + (size_t)(n0 + srow) * K + scol;

  for (int k0 = 0; k0 < K; k0 += 32) {
    gload_lds16(Ag + k0,            &As[w * 32][0]);
    gload_lds16(Ag + 16 * K + k0,   &As[w * 32 + 16][0]);
    gload_lds16(Bg + k0,            &Bs[w * 32][0]);
    gload_lds16(Bg + 16 * K + k0,   &Bs[w * 32 + 16][0]);
    __syncthreads();
    bf16x8 af[4], bfr[4];
    #pragma unroll
    for (int m = 0; m < 4; ++m) af[m] = *(bf16x8*)&As[wr * 64 + m * 16 + lr][lg * 8];
    #pragma unroll
    for (int n = 0; n < 4; ++n) bfr[n] = *(bf16x8*)&Bs[wc * 64 + n * 16 + lr][lg * 8];
    #pragma unroll
    for (int m = 0; m < 4; ++m)
      #pragma unroll
      for (int n = 0; n < 4; ++n)
        acc[m][n] = __builtin_amdgcn_mfma_f32_16x16x32_bf16(af[m], bfr[n], acc[m][n], 0, 0, 0);
    __syncthreads();
  }

  const int crow = m0 + wr * 64 + lg * 4;
  const int ccol = n0 + wc * 64 + lr;
  #pragma unroll
  for (int n = 0; n < 4; ++n) {
    int gc = ccol + n * 16;
    float bn = bias ? bias[gc] : 0.f;
    #pragma unroll
    for (int m = 0; m < 4; ++m) {
      #pragma unroll
      for (int reg = 0; reg < 4; ++reg) {
        int gr = crow + m * 16 + reg;
        float v = acc[m][n][reg] + bn;
        if (HASRES) v += R[(size_t)gr * N + gc];
        if (RELU) v = fmaxf(v, 0.f);
        if (WF32) C[(size_t)gr * N + gc] = v;
        if (WBF16) Cb[(size_t)gr * N + gc] = (__bf16)v;
      }
    }
  }
}

// ---------------- tiny-M GEMM: C[MR,N] = act(A[MR,K] @ W^T + bias) [* vs] ----------
// One wave per output column n. Coalesced weight reads, 64-lane shuffle reduce.
template<int MR, bool RELU, bool MASK>
__global__ __launch_bounds__(256) void tinygemm_kernel(
    const float* __restrict__ A, const float* __restrict__ W,
    const float* __restrict__ bias, const int* __restrict__ vs,
    float* __restrict__ C, int N, int K) {
  int n = blockIdx.x * 4 + (threadIdx.x >> 6);
  int lane = threadIdx.x & 63;
  if (n >= N) return;
  const float* wr = W + (size_t)n * K;
  float acc[MR];
  #pragma unroll
  for (int m = 0; m < MR; ++m) acc[m] = 0.f;
  for (int k = lane; k < K; k += 64) {
    float wv = wr[k];
    #pragma unroll
    for (int m = 0; m < MR; ++m)
      acc[m] += A[(size_t)m * K + k] * wv;
  }
  #pragma unroll
  for (int m = 0; m < MR; ++m) {
    #pragma unroll
    for (int off = 32; off; off >>= 1) acc[m] += __shfl_xor(acc[m], off);
  }
  if (lane == 0) {
    float bn = bias ? bias[n] : 0.f;
    #pragma unroll
    for (int m = 0; m < MR; ++m) {
      float v = acc[m] + bn;
      if (RELU) v = fmaxf(v, 0.f);
      if (MASK) v *= (float)vs[m];
      C[(size_t)m * N + n] = v;
    }
  }
}

// ---------------- MFMA flash attention (bf16 qkv in, bf16 O out) ----------------
__global__ __launch_bounds__(256) void attn_mfma_kernel(const __bf16* __restrict__ qkv,
                                                        __bf16* __restrict__ ob) {
  __shared__ __bf16 Ks[64][72];
  __shared__ __bf16 Vt[64][72];
  __shared__ __bf16 Ps[4][16][72];

  const int tid = threadIdx.x;
  const int wave = tid >> 6;
  const int lane = tid & 63;
  const int lr = lane & 15;
  const int lg = lane >> 4;
  const int bh = blockIdx.y;
  const int b = bh >> 3, h = bh & 7;
  const int q0 = blockIdx.x * 64;

  const __bf16* base = qkv + (size_t)b * LQ * 1536;

  bf16x8 aq[2];
  {
    const int qrow = q0 + wave * 16 + lr;
    const __bf16* qp = base + (size_t)qrow * 1536 + h * 64 + lg * 8;
    aq[0] = *(const bf16x8*)qp;
    aq[1] = *(const bf16x8*)(qp + 32);
  }

  float m[4], l[4];
  f32x4 o_acc[4];
  #pragma unroll
  for (int r = 0; r < 4; ++r) { m[r] = -1e30f; l[r] = 0.f; }
  #pragma unroll
  for (int df = 0; df < 4; ++df) o_acc[df] = f32x4{0.f, 0.f, 0.f, 0.f};

  for (int kt = 0; kt < LQ / 64; ++kt) {
    __syncthreads();
    #pragma unroll
    for (int p2 = 0; p2 < 2; ++p2) {
      int idx = tid + p2 * 256;
      int row = idx >> 3;
      int d0 = (idx & 7) * 8;
      const __bf16* kp = base + (size_t)(kt * 64 + row) * 1536 + 512 + h * 64 + d0;
      *(bf16x8*)&Ks[row][d0] = *(const bf16x8*)kp;
      bf16x8 vb = *(const bf16x8*)(kp + 512);
      int pc = (row & 7) + 8 * ((row >> 3) ^ (d0 >> 3));
      #pragma unroll
      for (int i = 0; i < 8; ++i)
        Vt[d0 + i][pc] = vb[i];
    }
    __syncthreads();

    f32x4 s[4];
    #pragma unroll
    for (int f = 0; f < 4; ++f) {
      f32x4 acc = f32x4{0.f, 0.f, 0.f, 0.f};
      #pragma unroll
      for (int c = 0; c < 2; ++c) {
        bf16x8 bk = *(bf16x8*)&Ks[f * 16 + lr][c * 32 + lg * 8];
        acc = __builtin_amdgcn_mfma_f32_16x16x32_bf16(aq[c], bk, acc, 0, 0, 0);
      }
      s[f] = acc * 0.125f;
    }

    #pragma unroll
    for (int r = 0; r < 4; ++r) {
      float rm = fmaxf(fmaxf(s[0][r], s[1][r]), fmaxf(s[2][r], s[3][r]));
      rm = fmaxf(rm, __shfl_xor(rm, 1));
      rm = fmaxf(rm, __shfl_xor(rm, 2));
      rm = fmaxf(rm, __shfl_xor(rm, 4));
      rm = fmaxf(rm, __shfl_xor(rm, 8));
      float nm = fmaxf(m[r], rm);
      float cor = __expf(m[r] - nm);
      m[r] = nm;
      float rs = 0.f;
      #pragma unroll
      for (int f = 0; f < 4; ++f) {
        float p = __expf(s[f][r] - nm);
        s[f][r] = p;
        rs += p;
      }
      rs += __shfl_xor(rs, 1);
      rs += __shfl_xor(rs, 2);
      rs += __shfl_xor(rs, 4);
      rs += __shfl_xor(rs, 8);
      l[r] = l[r] * cor + rs;
      #pragma unroll
      for (int df = 0; df < 4; ++df) o_acc[df][r] *= cor;
    }

    #pragma unroll
    for (int f = 0; f < 4; ++f)
      #pragma unroll
      for (int r = 0; r < 4; ++r)
        Ps[wave][lg * 4 + r][f * 16 + lr] = (__bf16)s[f][r];

    #pragma unroll
    for (int kc = 0; kc < 2; ++kc) {
      bf16x8 ap = *(bf16x8*)&Ps[wave][lr][kc * 32 + lg * 8];
      #pragma unroll
      for (int df = 0; df < 4; ++df) {
        int vrow = df * 16 + lr;
        int pb = (((4 * kc + lg) ^ ((vrow >> 3) & 7)) << 3);
        bf16x8 bv = *(bf16x8*)&Vt[vrow][pb];
        o_acc[df] = __builtin_amdgcn_mfma_f32_16x16x32_bf16(ap, bv, o_acc[df], 0, 0, 0);
      }
    }
  }

  __bf16* orow = ob + ((size_t)(b * LQ) + q0 + wave * 16) * DQ + h * 64;
  #pragma unroll
  for (int r = 0; r < 4; ++r) {
    float inv = 1.f / l[r];
    #pragma unroll
    for (int df = 0; df < 4; ++df)
      orow[(size_t)(lg * 4 + r) * DQ + df * 16 + lr] = (__bf16)(o_acc[df][r] * inv);
  }
}

// ---------------- LayerNorm over D=512 (writes f32 + bf16) ----------------
__global__ __launch_bounds__(256) void ln_kernel(const float* __restrict__ t,
    const float* __restrict__ g, const float* __restrict__ bb,
    float* __restrict__ xo, __bf16* __restrict__ xb) {
  int row = blockIdx.x;
  const float* tr = t + (size_t)row * DQ;
  int tid = threadIdx.x;
  float v0 = tr[tid], v1 = tr[tid + 256];
  float s = v0 + v1, ss = v0 * v0 + v1 * v1;
  #pragma unroll
  for (int off = 32; off; off >>= 1) { s += __shfl_xor(s, off); ss += __shfl_xor(ss, off); }
  __shared__ float rs[4], rss[4];
  int w = tid >> 6;
  if ((tid & 63) == 0) { rs[w] = s; rss[w] = ss; }
  __syncthreads();
  s = rs[0] + rs[1] + rs[2] + rs[3];
  ss = rss[0] + rss[1] + rss[2] + rss[3];
  float mean = s * (1.f / 512.f);
  float var = ss * (1.f / 512.f) - mean * mean;
  float r = rsqrtf(var + 1e-5f);
  float* xr = xo + (size_t)row * DQ;
  __bf16* xbr = xb + (size_t)row * DQ;
  float o0 = (v0 - mean) * r * g[tid] + bb[tid];
  float o1 = (v1 - mean) * r * g[tid + 256] + bb[tid + 256];
  xr[tid] = o0; xr[tid + 256] = o1;
  xbr[tid] = (__bf16)o0; xbr[tid + 256] = (__bf16)o1;
}

// ---------------- start/end logits ----------------
__global__ __launch_bounds__(256) void logits_kernel(const float* __restrict__ hidden,
    const float* __restrict__ sw, const float* __restrict__ sb,
    const float* __restrict__ ew, const float* __restrict__ eb,
    float* __restrict__ osl, float* __restrict__ oel) {
  int row = blockIdx.x * 4 + (threadIdx.x >> 6);
  int lane = threadIdx.x & 63;
  const float* hr = hidden + (size_t)row * DQ;
  float a = 0.f, b2 = 0.f;
  #pragma unroll
  for (int i = 0; i < 8; ++i) {
    int d = lane + i * 64;
    float h = hr[d];
    a += h * sw[d];
    b2 += h * ew[d];
  }
  #pragma unroll
  for (int off = 32; off; off >>= 1) { a += __shfl_xor(a, off); b2 += __shfl_xor(b2, off); }
  if (lane == 0) { osl[row] = a + sb[0]; oel[row] = b2 + eb[0]; }
}

// ---------------- top-5 per (b, which) ----------------
__global__ void topk_kernel(const float* __restrict__ slog, const float* __restrict__ elog,
                            int* __restrict__ sidx, int* __restrict__ eidx) {
  int b = blockIdx.x & 3;
  int which = blockIdx.x >> 2;
  const float* lg = (which ? elog : slog) + (size_t)b * LQ;
  int* outp = (which ? eidx : sidx) + b * KQ;
  int lane = threadIdx.x;
  int ch[KQ];
  for (int k = 0; k < KQ; ++k) {
    float bv = -1e38f; int bi = 1 << 30;
    for (int i = lane; i < LQ; i += 64) {
      bool skip = false;
      for (int t = 0; t < k; ++t) if (ch[t] == i) skip = true;
      float v = lg[i];
      if (!skip && (v > bv || (v == bv && i < bi))) { bv = v; bi = i; }
    }
    #pragma unroll
    for (int off = 32; off; off >>= 1) {
      float ov = __shfl_xor(bv, off); int oi = __shfl_xor(bi, off);
      if (ov > bv || (ov == bv && oi < bi)) { bv = ov; bi = oi; }
    }
    ch[k] = bi;
    if (lane == 0) outp[k] = bi;
  }
}

// ---------------- validity + stable compaction order ----------------
__global__ void vo_kernel(const int* __restrict__ sidx, const int* __restrict__ eidx,
                          int* __restrict__ order, int* __restrict__ vs) {
  int b = threadIdx.x;
  if (b >= BQ) return;
  int val[KQ];
  for (int k = 0; k < KQ; ++k) {
    int s = sidx[b * KQ + k], e = eidx[b * KQ + k];
    val[k] = (e >= s && (e - s) < MAXMQ) ? 1 : 0;
  }
  int j = 0;
  for (int k = 0; k < KQ; ++k) if (val[k])  { order[b * KQ + j] = k; vs[b * KQ + j] = 1; ++j; }
  for (int k = 0; k < KQ; ++k) if (!val[k]) { order[b * KQ + j] = k; vs[b * KQ + j] = 0; ++j; }
}

// ---------------- span features, gathered in compacted order ----------------
__global__ __launch_bounds__(256) void feat_kernel(const float* __restrict__ hidden,
    const int* __restrict__ sidx, const int* __restrict__ eidx,
    const int* __restrict__ order, float* __restrict__ feat) {
  int row = blockIdx.x;            // b*K + j (compacted position)
  int b = row / KQ;
  int k = order[row];              // original candidate index
  int si = sidx[b * KQ + k], ei = eidx[b * KQ + k];
  const float* hs = hidden + ((size_t)(b * LQ + si)) * DQ;
  const float* he = hidden + ((size_t)(b * LQ + ei)) * DQ;
  float* fr = feat + (size_t)row * (3 * DQ);
  for (int d = threadIdx.x; d < DQ; d += 256) {
    float a = hs[d], c = he[d];
    fr[d] = a; fr[DQ + d] = c; fr[2 * DQ + d] = a * c;
  }
}

// ---------------- scores ----------------
__global__ __launch_bounds__(256) void scores_kernel(const float* __restrict__ cand,
    const float* __restrict__ mp, const float* __restrict__ u, const float* __restrict__ ebias,
    float* __restrict__ oscores) {
  int gw = blockIdx.x * 4 + (threadIdx.x >> 6);   // (b*K+j)*64 + c
  int lane = threadIdx.x & 63;
  int bj = gw >> 6;
  const float* ce = cand + (size_t)gw * DQ;
  const float* ur = u + (size_t)bj * DQ;
  const float* mr = mp + (size_t)bj * DQ;
  float s = 0.f;
  #pragma unroll
  for (int i = 0; i < 8; ++i) {
    int e = lane + i * 64;
    s += ce[e] * ur[e] + mr[e] * ebias[e];
  }
  #pragma unroll
  for (int off = 32; off; off >>= 1) s += __shfl_xor(s, off);
  if (lane == 0) oscores[gw] = s;
}

extern "C" void kernel_launch(void* const* d_in, const int* in_sizes, int n_in,
                              void* d_out, int out_size, void* d_ws, size_t ws_size,
                              hipStream_t stream) {
  const int*   token_ids = (const int*)d_in[0];
  const float* cand    = (const float*)d_in[1];
  const float* tok_emb = (const float*)d_in[2];
  const float* pos_emb = (const float*)d_in[3];
  const float* ain_w   = (const float*)d_in[4];
  const float* ain_b   = (const float*)d_in[5];
  const float* aout_w  = (const float*)d_in[6];
  const float* aout_b  = (const float*)d_in[7];
  const float* ln1g    = (const float*)d_in[8];
  const float* ln1b    = (const float*)d_in[9];
  const float* fw1     = (const float*)d_in[10];
  const float* fb1     = (const float*)d_in[11];
  const float* fw2     = (const float*)d_in[12];
  const float* fb2     = (const float*)d_in[13];
  const float* ln2g    = (const float*)d_in[14];
  const float* ln2b    = (const float*)d_in[15];
  const float* sw      = (const float*)d_in[16];
  const float* sb      = (const float*)d_in[17];
  const float* ew      = (const float*)d_in[18];
  const float* eb      = (const float*)d_in[19];
  const float* sp_w1   = (const float*)d_in[20];
  const float* sp_b1   = (const float*)d_in[21];
  const float* sp_w2   = (const float*)d_in[22];
  const float* sp_b2   = (const float*)d_in[23];
  const float* m_w     = (const float*)d_in[24];
  const float* m_b     = (const float*)d_in[25];
  const float* e_w     = (const float*)d_in[26];
  const float* e_b     = (const float*)d_in[27];

  const int M = BQ * LQ;           // 8192
  float* out = (float*)d_out;
  float* out_span   = out;                  // [4,5,512]
  float* out_sl     = out + 10240;          // [4,2048]
  float* out_el     = out + 18432;          // [4,2048]
  float* out_hidden = out + 26624;          // [4,2048,512]
  float* out_scores = out + 4220928;        // [4,5,64]

  float* ws  = (float*)d_ws;
  float* X    = ws;                               // f32 [8192,512]
  float* T    = ws + 4194304;                     // f32 [8192,512]
  __bf16* BIGb = (__bf16*)(ws + 8388608);         // bf16 [8192,2048]
  __bf16* Xb   = (__bf16*)(ws + 16777216);        // bf16 [8192,512]
  __bf16* Ob   = (__bf16*)(ws + 18874368);        // bf16 [8192,512]
  __bf16* ain_wb  = (__bf16*)(ws + 20971520);
  __bf16* aout_wb = (__bf16*)(ws + 21757952);
  __bf16* fw1b    = (__bf16*)(ws + 22020096);
  __bf16* fw2b    = (__bf16*)(ws + 23068672);
  float* e_wT     = ws + 24117248;                // f32 [512,512] transposed
  int*   SIDX  = (int*)(ws + 29360128);
  int*   EIDX  = SIDX + 20;
  int*   ORDER = EIDX + 20;
  int*   VS    = ORDER + 20;
  float* FEAT    = ws + 29360208;                 // [20,1536]
  float* SPANH   = FEAT + 20 * 1536;              // [20,512]
  float* MP      = SPANH + 10240;                 // [20,512]
  float* U       = MP + 10240;                    // [20,512]

  // weight prep
  cvt_kernel<<<768, 256, 0, stream>>>(ain_w,  ain_wb,  2 * 1536 * 512);
  cvt_kernel<<<256, 256, 0, stream>>>(aout_w, aout_wb, 2 * 512 * 512);
  cvt_kernel<<<1024, 256, 0, stream>>>(fw1,   fw1b,    2 * 2048 * 512);
  cvt_kernel<<<1024, 256, 0, stream>>>(fw2,   fw2b,    2 * 512 * 2048);
  transpose512_kernel<<<256, 256, 0, stream>>>(e_w, e_wT);

  embed_kernel<<<M, 256, 0, stream>>>(token_ids, tok_emb, pos_emb, X, Xb);

  for (int l = 0; l < 2; ++l) {
    float* Xout = (l == 1) ? out_hidden : X;
    // qkv = x @ in_w^T + in_b  -> bf16
    bgemm_kernel<false, false, false, true><<<dim3(12, 64), 256, 0, stream>>>(
        Xb, ain_wb + (size_t)l * 1536 * 512, ain_b + l * 1536, nullptr,
        nullptr, BIGb, M, 1536, 512);
    attn_mfma_kernel<<<dim3(LQ / 64, BQ * HQ), 256, 0, stream>>>(BIGb, Ob);
    // t = x + o @ out_w^T + out_b  -> f32
    bgemm_kernel<false, true, true, false><<<dim3(4, 64), 256, 0, stream>>>(
        Ob, aout_wb + (size_t)l * 512 * 512, aout_b + l * 512, X,
        T, nullptr, M, 512, 512);
    ln_kernel<<<M, 256, 0, stream>>>(T, ln1g + l * 512, ln1b + l * 512, X, Xb);
    // ffn1: relu(x @ w1^T + b1) -> bf16
    bgemm_kernel<true, false, false, true><<<dim3(16, 64), 256, 0, stream>>>(
        Xb, fw1b + (size_t)l * 2048 * 512, fb1 + l * 2048, nullptr,
        nullptr, BIGb, M, 2048, 512);
    // ffn2: x + h @ w2^T + b2 -> f32
    bgemm_kernel<false, true, true, false><<<dim3(4, 64), 256, 0, stream>>>(
        BIGb, fw2b + (size_t)l * 512 * 2048, fb2 + l * 512, X,
        T, nullptr, M, 512, 2048);
    ln_kernel<<<M, 256, 0, stream>>>(T, ln2g + l * 512, ln2b + l * 512, Xout, Xb);
  }

  // heads (hidden now lives in out_hidden)
  logits_kernel<<<M / 4, 256, 0, stream>>>(out_hidden, sw, sb, ew, eb, out_sl, out_el);
  topk_kernel<<<8, 64, 0, stream>>>(out_sl, out_el, SIDX, EIDX);
  vo_kernel<<<1, 64, 0, stream>>>(SIDX, EIDX, ORDER, VS);
  feat_kernel<<<20, 256, 0, stream>>>(out_hidden, SIDX, EIDX, ORDER, FEAT);
  // span MLP (compacted order; mask on second layer)
  tinygemm_kernel<20, true, false><<<128, 256, 0, stream>>>(
      FEAT, sp_w1, sp_b1, nullptr, SPANH, 512, 1536);
  tinygemm_kernel<20, false, true><<<128, 256, 0, stream>>>(
      SPANH, sp_w2, sp_b2, VS, out_span, 512, 512);
  // mention proj + entity proj
  tinygemm_kernel<20, false, false><<<128, 256, 0, stream>>>(
      out_span, m_w, m_b, nullptr, MP, 512, 512);
  tinygemm_kernel<20, false, false><<<128, 256, 0, stream>>>(
      MP, e_wT, nullptr, nullptr, U, 512, 512);
  scores_kernel<<<320, 256, 0, stream>>>(cand, MP, U, e_b, out_scores);
}